// Round 7
// baseline (360.958 us; speedup 1.0000x reference)
//
#include <hip/hip_runtime.h>
#include <hip/hip_bf16.h>

// GQA block for MI355X. bf16 MFMA 16x16x32 (QK^T, projections), f16 MFMA
// 16x16x16 (PV - P stays in registers via the S^T trick), fp32 accumulation.
//
// S^T trick: compute S^T = K.Q^T (A=K-frag, B=Q-frag). C-layout gives lane:
// q = lane&15, key = quad*4+reg - exactly the A-operand layout of
// mfma_f32_16x16x16f16 for O = P.V. No P LDS round-trip (the bank-conflict
// source in the rd-2/6 design); fixed-max exp2 softmax (arg clamped at -13
// so all P are normal f16) => per-lane row sums, one shuffle reduction +
// width-16 shuffle broadcast at kernel end.
//
// STAGING COVERAGE AUDIT (the rd-3/4/5 NaN root cause was under-coverage):
//   K tile 64x128 shorts = 1024 short8; 512 thr x 2 stores (rows kR,kR+32) OK
//   V tile 128x64 shorts = 1024 short8; 512 thr x 2 stores (rows vR,vR+64) OK

typedef __attribute__((ext_vector_type(8))) short short8;
typedef __attribute__((ext_vector_type(4))) short short4v;
typedef __attribute__((ext_vector_type(4))) float float4v;
typedef __attribute__((ext_vector_type(4))) _Float16 half4;

#define C1F 0.12751743f   // (1/sqrt(128)) * log2(e)

__device__ __forceinline__ short f2bf(float x) {
    __hip_bfloat16 h = __float2bfloat16(x);
    short s; __builtin_memcpy(&s, &h, sizeof(s)); return s;
}
__device__ __forceinline__ short f2h(float x) {
    _Float16 h = (_Float16)x;
    short s; __builtin_memcpy(&s, &h, sizeof(s)); return s;
}

__device__ __forceinline__ void gl16(const short* g, short* l) {
    __builtin_amdgcn_global_load_lds(
        (const __attribute__((address_space(1))) void*)g,
        (__attribute__((address_space(3))) void*)l, 16, 0, 0);
}

// ---------------- fp32 -> bf16 elementwise ----------------
__global__ __launch_bounds__(256) void cvt_bf16_kernel(const float* __restrict__ in,
                                                       short* __restrict__ out, int n) {
    int i = (blockIdx.x * 256 + threadIdx.x) * 4;
    if (i >= n) return;
    float4 v = *(const float4*)(in + i);
    short4v o;
    o[0] = f2bf(v.x); o[1] = f2bf(v.y); o[2] = f2bf(v.z); o[3] = f2bf(v.w);
    *(short4v*)(out + i) = o;
}

// ---------------- W[K,N] fp32 -> Wt[N,K] bf16 ----------------
__global__ __launch_bounds__(256) void transpose_cvt_kernel(const float* __restrict__ W,
                                                            short* __restrict__ Wt,
                                                            int K, int N) {
    __shared__ float tile[32][33];
    int n0 = blockIdx.x * 32, k0 = blockIdx.y * 32;
    int tx = threadIdx.x & 31, ty = threadIdx.x >> 5;
#pragma unroll
    for (int i = 0; i < 4; ++i) {
        int kk = ty + i * 8;
        tile[kk][tx] = W[(size_t)(k0 + kk) * N + n0 + tx];
    }
    __syncthreads();
#pragma unroll
    for (int i = 0; i < 4; ++i) {
        int nn = ty + i * 8;
        Wt[(size_t)(n0 + nn) * K + k0 + tx] = f2bf(tile[tx][nn]);
    }
}

// ---------------- GEMM (m97 pattern): C = A[M,K] @ Bt[N,K]^T + bias ----------------
// 128x128 tile, BK=32, 4 waves. global_load_lds width-16 staging.
// mode 0: fused QKV epilogue (Q->O0 bf16 [*,2048], K->O1 bf16 [*,512],
//         V->O2 f16 transposed [512,4096])
// mode 1: fp32 out Of [*,2048] + b0
__global__ __launch_bounds__(256) void gemm_dma_kernel(
    const short* __restrict__ A, const short* __restrict__ Bt,
    const float* __restrict__ b0, const float* __restrict__ b1, const float* __restrict__ b2,
    short* __restrict__ O0, short* __restrict__ O1, short* __restrict__ O2,
    float* __restrict__ Of, int K, int mode) {
    __shared__ short As[128 * 32];
    __shared__ short Bs[128 * 32];
    const int t = threadIdx.x, lane = t & 63, w = t >> 6;
    const int l15 = lane & 15, quad = lane >> 4;
    const int wm = (w & 1) * 64, wn = (w >> 1) * 64;
    const int m0 = blockIdx.y * 128, n0 = blockIdx.x * 128;
    const int r4 = lane >> 2, c8 = (lane & 3) * 8;
    const short* ga = A + (size_t)(m0 + w * 16 + r4) * K + c8;
    const short* gb = Bt + (size_t)(n0 + w * 16 + r4) * K + c8;
    short* lA = As + (w * 16) * 32;   // wave-uniform LDS base, dst = base + lane*16B
    short* lB = Bs + (w * 16) * 32;

    float4v acc[4][4] = {};

    for (int k0 = 0; k0 < K; k0 += 32) {
        gl16(ga + k0, lA);
        gl16(ga + (size_t)64 * K + k0, lA + 64 * 32);
        gl16(gb + k0, lB);
        gl16(gb + (size_t)64 * K + k0, lB + 64 * 32);
        __syncthreads();
        short8 af[4], bfr[4];
#pragma unroll
        for (int i = 0; i < 4; ++i)
            af[i] = *(const short8*)(As + (wm + i * 16 + l15) * 32 + quad * 8);
#pragma unroll
        for (int j = 0; j < 4; ++j)
            bfr[j] = *(const short8*)(Bs + (wn + j * 16 + l15) * 32 + quad * 8);
#pragma unroll
        for (int i = 0; i < 4; ++i)
#pragma unroll
            for (int j = 0; j < 4; ++j)
                acc[i][j] = __builtin_amdgcn_mfma_f32_16x16x32_bf16(af[i], bfr[j], acc[i][j], 0, 0, 0);
        __syncthreads();
    }

#pragma unroll
    for (int i = 0; i < 4; ++i) {
#pragma unroll
        for (int j = 0; j < 4; ++j) {
            const int col = n0 + wn + j * 16 + l15;
            const int row0 = m0 + wm + i * 16 + quad * 4;
            if (mode == 1) {
                const float bc = b0[col];
#pragma unroll
                for (int r = 0; r < 4; ++r)
                    Of[(size_t)(row0 + r) * 2048 + col] = acc[i][j][r] + bc;
            } else if (col < 2048) {
                const float bc = b0[col];
#pragma unroll
                for (int r = 0; r < 4; ++r)
                    O0[(size_t)(row0 + r) * 2048 + col] = f2bf(acc[i][j][r] + bc);
            } else if (col < 2560) {
                const int c = col - 2048;
                const float bc = b1[c];
#pragma unroll
                for (int r = 0; r < 4; ++r)
                    O1[(size_t)(row0 + r) * 512 + c] = f2bf(acc[i][j][r] + bc);
            } else {
                const int c = col - 2560;
                const float bc = b2[c];
#pragma unroll
                for (int r = 0; r < 4; ++r)
                    O2[(size_t)c * 4096 + row0 + r] = f2h(acc[i][j][r] + bc);  // V is f16
            }
        }
    }
}

// ---------------- Flash attention, S^T formulation ----------------
// grid (S/64, G, B) = (32,4,2), 512 threads = 8 waves. Wave w: head =
// g + 4*(w&3) (jnp.tile: group = h % 4), q-rows = qt*64 + (w>>2)*32 .. +32
// (mi=2 tiles of 16). Qb/Kb bf16; Vt f16 [512,4096]. P never touches LDS.
__global__ __launch_bounds__(512, 2) void flash_kernel(
    const short* __restrict__ Qb, const short* __restrict__ Kb,
    const short* __restrict__ Vt, const int* __restrict__ mask,
    short* __restrict__ Ab) {
    __shared__ short Ks[64 * 136];   // [key][d] bf16, stride pad 136
    __shared__ short Vs[128 * 72];   // [d][key] f16, stride pad 72
    __shared__ float mb[64];         // per-key multiplier 1/0

    const int t = threadIdx.x;
    const int lane = t & 63, w = t >> 6;
    const int l15 = lane & 15, quad = lane >> 4;
    const int qt = blockIdx.x, g = blockIdx.y, b = blockIdx.z;
    const int h = g + 4 * (w & 3);
    const int q0 = qt * 64 + (w >> 2) * 32;

    // Q as B-operand frags: [n=q(lane&15)][k=quad*8+j], 2 mi x 4 ksteps
    short8 qf[2][4];
#pragma unroll
    for (int mi = 0; mi < 2; ++mi)
#pragma unroll
        for (int ks = 0; ks < 4; ++ks)
            qf[mi][ks] = *(const short8*)(Qb + (size_t)(b * 2048 + q0 + mi * 16 + l15) * 2048
                                          + h * 128 + ks * 32 + quad * 8);

    float4v o[2][8] = {};            // C-layout: col=l15=d, row=quad*4+r=q
    float rsum[2] = {0.f, 0.f};      // per-lane: q=l15, partial over this quad's keys

    // staging (coverage audited, 2 short8 stores each region per thread):
    //   K: kR in [0,32), rows kR+{0,32}; kC=(t&15)*8 -> 16 thr x 8 sh = 128/row
    //   V: vR in [0,64), rows vR+{0,64}; vC=(t&7)*8  ->  8 thr x 8 sh =  64/row
    const int kR = t >> 4, kC = (t & 15) * 8;
    const int vR = t >> 3, vC = (t & 7) * 8;
    const short* kg = Kb + (size_t)(b * 2048 + kR) * 512 + g * 128 + kC;
    const short* vg = Vt + (size_t)(g * 128 + vR) * 4096 + (size_t)b * 2048 + vC;

    for (int kt = 0; kt < 32; ++kt) {
        const int kb = kt * 64;
        short8 kv0 = *(const short8*)(kg + (size_t)(kb +  0) * 512);
        short8 kv1 = *(const short8*)(kg + (size_t)(kb + 32) * 512);
        short8 vv0 = *(const short8*)(vg + kb);
        short8 vv1 = *(const short8*)(vg + (size_t)64 * 4096 + kb);
        float mv = 0.f;
        if (t < 64) mv = mask[b * 2048 + kb + t] ? 1.0f : 0.0f;
        __syncthreads();   // all waves done reading previous tile
        *(short8*)(Ks + (kR +  0) * 136 + kC) = kv0;
        *(short8*)(Ks + (kR + 32) * 136 + kC) = kv1;
        *(short8*)(Vs + (vR +  0) * 72 + vC) = vv0;
        *(short8*)(Vs + (vR + 64) * 72 + vC) = vv1;
        if (t < 64) mb[t] = mv;
        __syncthreads();

        // S^T = K @ Q^T : A=K-frag (m=key), B=Q-frag (n=q)
        float4v s[2][4] = {};
#pragma unroll
        for (int ks = 0; ks < 4; ++ks) {
            short8 kf[4];
#pragma unroll
            for (int kt4 = 0; kt4 < 4; ++kt4)
                kf[kt4] = *(const short8*)(Ks + (kt4 * 16 + l15) * 136 + ks * 32 + quad * 8);
#pragma unroll
            for (int kt4 = 0; kt4 < 4; ++kt4) {
                s[0][kt4] = __builtin_amdgcn_mfma_f32_16x16x32_bf16(kf[kt4], qf[0][ks], s[0][kt4], 0, 0, 0);
                s[1][kt4] = __builtin_amdgcn_mfma_f32_16x16x32_bf16(kf[kt4], qf[1][ks], s[1][kt4], 0, 0, 0);
            }
        }
        // p = 2^max(s*C1, -13) * mask; all p normal f16 (or exact 0).
        // lane q=l15 holds keys kt4*16+quad*4+r
        half4 pf[2][4];
#pragma unroll
        for (int kt4 = 0; kt4 < 4; ++kt4) {
#pragma unroll
            for (int r = 0; r < 4; ++r) {
                const float mv2 = mb[kt4 * 16 + quad * 4 + r];  // quad-broadcast read
                float p0 = exp2f(fmaxf(s[0][kt4][r] * C1F, -13.0f)) * mv2;
                float p1 = exp2f(fmaxf(s[1][kt4][r] * C1F, -13.0f)) * mv2;
                rsum[0] += p0; rsum[1] += p1;
                pf[0][kt4][r] = (_Float16)p0;
                pf[1][kt4][r] = (_Float16)p1;
            }
        }
        // O += P @ V : A=pf (registers), B=V-frag [k=key=kt4*16+quad*4+i][n=d]
#pragma unroll
        for (int kt4 = 0; kt4 < 4; ++kt4)
#pragma unroll
            for (int dt = 0; dt < 8; ++dt) {
                half4 bv = *(const half4*)(Vs + (dt * 16 + l15) * 72 + kt4 * 16 + quad * 4);
                o[0][dt] = __builtin_amdgcn_mfma_f32_16x16x16f16(pf[0][kt4], bv, o[0][dt], 0, 0, 0);
                o[1][dt] = __builtin_amdgcn_mfma_f32_16x16x16f16(pf[1][kt4], bv, o[1][dt], 0, 0, 0);
            }
    }

    // rowsum: xor-reduce over the 4 quads (every lane ends with sum for q=l15),
    // invert, then width-16 shuffle-broadcast to lanes needing row q=quad*4+r.
    float rinv_src[2];
#pragma unroll
    for (int mi = 0; mi < 2; ++mi) {
        float v = rsum[mi];
        v += __shfl_xor(v, 16, 64);
        v += __shfl_xor(v, 32, 64);
        rinv_src[mi] = (v > 0.f) ? 1.f / v : 0.f;
    }
    const size_t ob = (size_t)(b * 2048 + q0) * 2048 + h * 128;
#pragma unroll
    for (int mi = 0; mi < 2; ++mi)
#pragma unroll
        for (int r = 0; r < 4; ++r) {
            const float rinv = __shfl(rinv_src[mi], quad * 4 + r, 16);  // from lane l15==q
#pragma unroll
            for (int dt = 0; dt < 8; ++dt)
                Ab[ob + (size_t)(mi * 16 + quad * 4 + r) * 2048 + dt * 16 + l15] =
                    f2bf(o[mi][dt][r] * rinv);
        }
}

extern "C" void kernel_launch(void* const* d_in, const int* in_sizes, int n_in,
                              void* d_out, int out_size, void* d_ws, size_t ws_size,
                              hipStream_t stream) {
    (void)in_sizes; (void)n_in; (void)out_size; (void)ws_size;
    const float* X  = (const float*)d_in[0];
    const int* mask = (const int*)d_in[1];
    const float* Wq = (const float*)d_in[2];
    const float* bq = (const float*)d_in[3];
    const float* Wk = (const float*)d_in[4];
    const float* bk = (const float*)d_in[5];
    const float* Wv = (const float*)d_in[6];
    const float* bv = (const float*)d_in[7];
    const float* Wo = (const float*)d_in[8];
    const float* bo = (const float*)d_in[9];
    float* out = (float*)d_out;

    char* ws = (char*)d_ws;
    short* Xb     = (short*)(ws + 0);          // 16 MB (reused as Ab)
    short* WqkvT  = (short*)(ws + 16777216);   // 12 MB [3072,2048]
    short* Wot    = (short*)(ws + 29360128);   //  8 MB
    short* Qb     = (short*)(ws + 37748736);   // 16 MB
    short* Kb     = (short*)(ws + 54525952);   //  4 MB
    short* Vt     = (short*)(ws + 58720256);   //  4 MB (f16)
    short* Ab     = Xb;

    const int M = 4096, HID = 2048, KV = 512;

    cvt_bf16_kernel<<<8192, 256, 0, stream>>>(X, Xb, M * HID);
    transpose_cvt_kernel<<<dim3(64, 64), 256, 0, stream>>>(Wq, WqkvT, HID, HID);
    transpose_cvt_kernel<<<dim3(16, 64), 256, 0, stream>>>(Wk, WqkvT + (size_t)2048 * 2048, HID, KV);
    transpose_cvt_kernel<<<dim3(16, 64), 256, 0, stream>>>(Wv, WqkvT + (size_t)2560 * 2048, HID, KV);
    transpose_cvt_kernel<<<dim3(64, 64), 256, 0, stream>>>(Wo, Wot, HID, HID);

    // fused Q|K|V projection: N = 3072
    gemm_dma_kernel<<<dim3(24, 32), 256, 0, stream>>>(
        Xb, WqkvT, bq, bk, bv, Qb, Kb, Vt, nullptr, HID, 0);

    flash_kernel<<<dim3(32, 4, 2), 512, 0, stream>>>(Qb, Kb, Vt, mask, Ab);

    gemm_dma_kernel<<<dim3(16, 32), 256, 0, stream>>>(
        Ab, Wot, bo, nullptr, nullptr, nullptr, nullptr, nullptr, out, HID, 1);
}